// Round 8
// baseline (151.604 us; speedup 1.0000x reference)
//
#include <hip/hip_runtime.h>

// NonLocalBlock (SAGAN non-local) fused pipeline for MI355X / gfx950.
// B=8, Cin=256, H=W=64 (HW=4096), Cout=512. Workspace (~46 MB of d_ws):
//   [0,16MB)   xT   fp16 [8][4096][256]
//   [16,20MB)  Q    fp16 [8][4096][64]
//   [20,21MB)  Kp   fp16 [8][1024][64]
//   [21,25MB)  V    fp16 [8][256][1024]
//   [25MB+0)   Wproj fp16 [384][256]; [25MB+512K) Wcat fp16 [512][512]
//   [26,46MB)  F    fp16 [8][320][4096]; att aliases F
//
// R7->R8: fix-only round. cvt_pkrtz returns __fp16x2 -> bit_cast to h2.
// (R6->R7 theory unchanged: m214-style 32x32 swapped QK^T, register P,
// permlane32_swap row-reduce, 80KB LDS -> 2 blocks/CU = 4 waves/SIMD.)

typedef _Float16 f16;
typedef f16 f16x4 __attribute__((ext_vector_type(4)));
typedef f16 f16x8 __attribute__((ext_vector_type(8)));
typedef f16 h2 __attribute__((ext_vector_type(2)));
typedef float f32x4 __attribute__((ext_vector_type(4)));
typedef float f32x16 __attribute__((ext_vector_type(16)));
typedef int int2v __attribute__((ext_vector_type(2)));

#define MFMA16(a, b, c) __builtin_amdgcn_mfma_f32_16x16x32_f16((a), (b), (c), 0, 0, 0)
#define MFMA32(a, b, c) __builtin_amdgcn_mfma_f32_32x32x16_f16((a), (b), (c), 0, 0, 0)

__device__ __forceinline__ void gload16(const void* src, void* dst_lds) {
  __builtin_amdgcn_global_load_lds(
      (const __attribute__((address_space(1))) void*)src,
      (__attribute__((address_space(3))) void*)dst_lds, 16, 0, 0);
}

__device__ __forceinline__ f16x8 cat8(f16x4 a, f16x4 b) {
  f16x8 r;
  r[0] = a[0]; r[1] = a[1]; r[2] = a[2]; r[3] = a[3];
  r[4] = b[0]; r[5] = b[1]; r[6] = b[2]; r[7] = b[3];
  return r;
}

__device__ __forceinline__ h2 pk2(float a, float b) {
  return __builtin_bit_cast(h2, __builtin_amdgcn_cvt_pkrtz(a, b));
}

__device__ __forceinline__ float asf(int x) { return __builtin_bit_cast(float, x); }
__device__ __forceinline__ int asi(float x) { return __builtin_bit_cast(int, x); }

// -------------------------------------------------------------------------
__global__ __launch_bounds__(256, 4)
void k_prep_w(const float* __restrict__ wt, const float* __restrict__ wp,
              const float* __restrict__ wg, const float* __restrict__ wo,
              const float* __restrict__ wr, const float* __restrict__ gamma,
              f16* __restrict__ Wproj, f16* __restrict__ Wcat) {
  int i = blockIdx.x * 256 + threadIdx.x;
  const float s = 0.08838834764831845f;    // sqrt(2/256)
  const float is2 = 0.7071067811865476f;   // 1/sqrt(2)
  if (i < 384 * 256) {
    float v = (i < 64 * 256) ? wt[i]
              : (i < 128 * 256 ? wp[i - 64 * 256] : wg[i - 128 * 256]);
    Wproj[i] = (f16)(v * s);
  } else {
    int j = i - 384 * 256;
    if (j < 512 * 512) {
      int r = j >> 9, c = j & 511;
      float v = (c < 256) ? wo[r * 256 + c] * (gamma[0] * s * is2)
                          : wr[r * 256 + (c - 256)] * (s * is2);
      Wcat[j] = (f16)v;
    }
  }
}

// -------------------------------------------------------------------------
// Transpose x [b][256][4096] fp32 -> xT [b][4096][256] fp16 via 64x64 LDS tiles.
__global__ __launch_bounds__(256, 4)
void k_transpose(const float* __restrict__ x, f16* __restrict__ xT) {
  __shared__ f16 tile[64 * 72];
  int b = blockIdx.z, nt = blockIdx.y, ct = blockIdx.x;
  int t = threadIdx.x;
  {
    int c = t >> 2, nch = (t & 3) * 16;
    const float* src = x + (((size_t)b * 256 + ct * 64 + c) << 12) + nt * 64 + nch;
    float4 v0 = *(const float4*)(src);
    float4 v1 = *(const float4*)(src + 4);
    float4 v2 = *(const float4*)(src + 8);
    float4 v3 = *(const float4*)(src + 12);
    f16x8 a = {(f16)v0.x, (f16)v0.y, (f16)v0.z, (f16)v0.w,
               (f16)v1.x, (f16)v1.y, (f16)v1.z, (f16)v1.w};
    f16x8 bb = {(f16)v2.x, (f16)v2.y, (f16)v2.z, (f16)v2.w,
                (f16)v3.x, (f16)v3.y, (f16)v3.z, (f16)v3.w};
    *(f16x8*)&tile[c * 72 + nch] = a;
    *(f16x8*)&tile[c * 72 + nch + 8] = bb;
  }
  __syncthreads();
  {
    int n = t >> 2, cch = (t & 3) * 16;
    f16 tmp[16];
#pragma unroll
    for (int i = 0; i < 16; i++) tmp[i] = tile[(cch + i) * 72 + n];
    f16x8 a, bb;
#pragma unroll
    for (int i = 0; i < 8; i++) { a[i] = tmp[i]; bb[i] = tmp[8 + i]; }
    f16* dst = xT + (((size_t)b * 4096 + nt * 64 + n) << 8) + ct * 64 + cch;
    *(f16x8*)dst = a;
    *(f16x8*)(dst + 8) = bb;
  }
}

// -------------------------------------------------------------------------
// Merged projection GEMM: out rows = Wproj rows [mt*64, mt*64+64).
// mt==0 -> theta -> Q[b][n][64]; mt>=1 -> phi|g -> F[b][jj][n].
__global__ __launch_bounds__(256, 2)
void k_gemm_projq(const f16* __restrict__ xT, const f16* __restrict__ Wproj,
                  f16* __restrict__ Q, f16* __restrict__ F) {
  __shared__ f16 Alds[64 * 64];
  __shared__ f16 Blds[128 * 64];
  int b = blockIdx.z, mt = blockIdx.y, nt = blockIdx.x;
  int lane = threadIdx.x & 63, wave = threadIdx.x >> 6;
  int wm = wave >> 1, wn = wave & 1;
  f32x4 acc[2][4];
#pragma unroll
  for (int mf = 0; mf < 2; mf++)
#pragma unroll
    for (int nf = 0; nf < 4; nf++) acc[mf][nf] = (f32x4){0, 0, 0, 0};
  const f16* Abase = Wproj + ((mt * 64) << 8);
  const f16* Bbase = xT + (((size_t)b * 4096 + nt * 128) << 8);
  for (int k0 = 0; k0 < 256; k0 += 64) {
    __syncthreads();
#pragma unroll
    for (int i = 0; i < 2; i++) {
      int chunk = i * 256 + threadIdx.x;
      int row = chunk >> 3, cc = chunk & 7, scc = cc ^ (row & 7);
      gload16(Abase + (row << 8) + k0 + scc * 8, (char*)Alds + (i * 256 + wave * 64) * 16);
    }
#pragma unroll
    for (int i = 0; i < 4; i++) {
      int chunk = i * 256 + threadIdx.x;
      int row = chunk >> 3, cc = chunk & 7, scc = cc ^ (row & 7);
      gload16(Bbase + (row << 8) + k0 + scc * 8, (char*)Blds + (i * 256 + wave * 64) * 16);
    }
    __syncthreads();
#pragma unroll
    for (int ks = 0; ks < 2; ks++) {
      int cb = ((lane >> 4) * 8 + ks * 32) * 2;
      f16x8 af[2], bf[4];
#pragma unroll
      for (int mf = 0; mf < 2; mf++) {
        int row = wm * 32 + mf * 16 + (lane & 15);
        af[mf] = *(const f16x8*)((const char*)Alds + row * 128 + (cb ^ ((row & 7) << 4)));
      }
#pragma unroll
      for (int nf = 0; nf < 4; nf++) {
        int row = wn * 64 + nf * 16 + (lane & 15);
        bf[nf] = *(const f16x8*)((const char*)Blds + row * 128 + (cb ^ ((row & 7) << 4)));
      }
#pragma unroll
      for (int mf = 0; mf < 2; mf++)
#pragma unroll
        for (int nf = 0; nf < 4; nf++) acc[mf][nf] = MFMA16(af[mf], bf[nf], acc[mf][nf]);
    }
  }
#pragma unroll
  for (int mf = 0; mf < 2; mf++)
#pragma unroll
    for (int nf = 0; nf < 4; nf++)
#pragma unroll
      for (int r = 0; r < 4; r++) {
        int jl = wm * 32 + mf * 16 + (lane >> 4) * 4 + r;  // 0..63
        int n = nt * 128 + wn * 64 + nf * 16 + (lane & 15);
        f16 v = (f16)acc[mf][nf][r];
        if (mt == 0)
          Q[(((size_t)b * 4096 + n) << 6) + jl] = v;
        else
          F[(((size_t)b * 320 + (mt - 1) * 64 + jl) << 12) + n] = v;
      }
}

// -------------------------------------------------------------------------
// 2x2 maxpool: F[b][jj][4096] -> jj<64: Kp[b][m][jj] (phi), jj>=64: V[b][jj-64][m].
__global__ __launch_bounds__(256, 4)
void k_pool(const f16* __restrict__ F, f16* __restrict__ Kp, f16* __restrict__ V) {
  int id = blockIdx.x * 256 + threadIdx.x;  // < 8*320*32 = 81920
  int ph = id & 31;
  int rest = id >> 5;
  int jj = rest % 320;
  int b = rest / 320;
  const f16x8* r0 = (const f16x8*)(F + (((size_t)b * 320 + jj) << 12) + ph * 128);
  const f16x8* r1 = r0 + 8;
  f16 outv[32];
#pragma unroll
  for (int ch = 0; ch < 8; ch++) {
    f16x8 u = r0[ch], v = r1[ch];
#pragma unroll
    for (int p = 0; p < 4; p++) {
      float m1 = fmaxf(fmaxf((float)u[2 * p], (float)u[2 * p + 1]),
                       fmaxf((float)v[2 * p], (float)v[2 * p + 1]));
      outv[ch * 4 + p] = (f16)m1;
    }
  }
  int m0 = ph * 32;
  if (jj < 64) {
#pragma unroll
    for (int p = 0; p < 32; p++)
      Kp[((size_t)b * 1024 + m0 + p) * 64 + jj] = outv[p];
  } else {
    f16* dst = V + (((size_t)b * 256 + (jj - 64)) << 10) + m0;
#pragma unroll
    for (int c8 = 0; c8 < 4; c8++) {
      f16x8 w;
#pragma unroll
      for (int i = 0; i < 8; i++) w[i] = outv[c8 * 8 + i];
      *(f16x8*)(dst + c8 * 8) = w;
    }
  }
}

// -------------------------------------------------------------------------
// Flash attention (m214-style 32x32): Q [4096][64], K [1024][64], V [256][1024]
// -> att [n][c]. 512 thr = 8 waves = 2 rowgroups(32q) x 4 chgroups(64ch).
// Swapped QK^T (MFMA32(K,Q)): lane holds q-row (lane&31)'s scores; P stays in
// registers and feeds PV's A-operand directly. LDS = K/V dbuf only (80KB).
__global__ __launch_bounds__(512, 4)
void k_flash(const f16* __restrict__ Q, const f16* __restrict__ Kp,
             const f16* __restrict__ V, f16* __restrict__ att) {
  __shared__ f16 Klds[2][64 * 64];    // [key][ch] swizzled, 8KB each
  __shared__ f16 Vlds[2][256 * 64];   // [ch][key] swizzled, 32KB each
  int b = blockIdx.y, qt = blockIdx.x;
  int tid = threadIdx.x;
  int lane = tid & 63, wave = tid >> 6;
  int rg = wave >> 2, cg = wave & 3;   // rowgroup 0..1, chgroup 0..3
  int l31 = lane & 31, h5 = lane >> 5;
  const f16* Kb = Kp + ((size_t)b << 16);
  const f16* Vb = V + ((size_t)b << 18);
  const float L2E = 1.44269504f;

  // Q B-fragments: qf[t] = Q[q=l31-row][ch {16t+4h5+0..3, 16t+8+4h5+0..3}]
  const f16* Qrow = Q + (((size_t)b * 4096 + qt * 64 + rg * 32 + l31) << 6);
  f16x8 qf[4];
#pragma unroll
  for (int t = 0; t < 4; t++) {
    f16x4 lo = *(const f16x4*)(Qrow + t * 16 + 4 * h5);
    f16x4 hi = *(const f16x4*)(Qrow + t * 16 + 8 + 4 * h5);
    qf[t] = cat8(lo, hi);
  }
  f32x16 o0, o1;
#pragma unroll
  for (int i = 0; i < 16; i++) { o0[i] = 0.f; o1[i] = 0.f; }
  float m = -1e30f, lsum = 0.f;

#define STAGE(bufi, kt)                                                          \
  {                                                                              \
    {                                                                            \
      int chunk = tid;                                                           \
      int row = chunk >> 3, cc = chunk & 7, scc = cc ^ (row & 7);                \
      gload16(Kb + (((kt) * 64 + row) << 6) + scc * 8,                           \
              (char*)&Klds[bufi][0] + chunk * 16);                               \
    }                                                                            \
    _Pragma("unroll") for (int i = 0; i < 4; i++) {                              \
      int chunk = i * 512 + tid;                                                 \
      int row = chunk >> 3, cc = chunk & 7, scc = cc ^ (row & 7);                \
      gload16(Vb + ((size_t)row << 10) + (kt) * 64 + scc * 8,                    \
              (char*)&Vlds[bufi][0] + chunk * 16);                               \
    }                                                                            \
  }

  STAGE(0, 0);
  __syncthreads();
  int buf = 0;
  int swk = (l31 & 7) << 4;  // swizzle for K rows l31 / l31+32 (same &7)
  for (int kt = 0; kt < 16; ++kt) {
    if (kt < 15) STAGE(buf ^ 1, kt + 1);
    // ---- S^T = K Q^T: S0 keys 0..31, S1 keys 32..63 (rows crow(reg,h5))
    f32x16 S0, S1;
#pragma unroll
    for (int i = 0; i < 16; i++) { S0[i] = 0.f; S1[i] = 0.f; }
    const char* Kbase = (const char*)&Klds[buf][0];
#pragma unroll
    for (int t = 0; t < 4; t++) {
      int ob = t * 32 + 8 * h5;
      f16x4 a0 = *(const f16x4*)(Kbase + l31 * 128 + (ob ^ swk));
      f16x4 a1 = *(const f16x4*)(Kbase + l31 * 128 + ((ob + 16) ^ swk));
      S0 = MFMA32(cat8(a0, a1), qf[t], S0);
      f16x4 b0 = *(const f16x4*)(Kbase + (l31 + 32) * 128 + (ob ^ swk));
      f16x4 b1 = *(const f16x4*)(Kbase + (l31 + 32) * 128 + ((ob + 16) ^ swk));
      S1 = MFMA32(cat8(b0, b1), qf[t], S1);
    }
    // ---- lane-local softmax over 64 keys (row q = l31; other half in lane^32)
    float mx = S0[0];
#pragma unroll
    for (int i = 1; i < 16; i++) mx = fmaxf(mx, S0[i]);
#pragma unroll
    for (int i = 0; i < 16; i++) mx = fmaxf(mx, S1[i]);
    int2v pr = __builtin_amdgcn_permlane32_swap(asi(mx), asi(mx), false, false);
    mx = fmaxf(asf(pr[0]), asf(pr[1]));  // own ∪ cross half
    bool trig = mx > m + 8.f;
    if (__any(trig)) {
      float mnew = fmaxf(m, mx);
      float corr = __builtin_amdgcn_exp2f((m - mnew) * L2E);
      m = mnew;
      lsum *= corr;
#pragma unroll
      for (int reg = 0; reg < 16; reg++) {
        float cr = __shfl(corr, (reg & 3) + 8 * (reg >> 2) + 4 * h5, 64);
        o0[reg] *= cr;
        o1[reg] *= cr;
      }
    }
    float e[32];
    float lp = 0.f;
#pragma unroll
    for (int i = 0; i < 16; i++) { e[i] = __builtin_amdgcn_exp2f((S0[i] - m) * L2E); lp += e[i]; }
#pragma unroll
    for (int i = 0; i < 16; i++) { e[16 + i] = __builtin_amdgcn_exp2f((S1[i] - m) * L2E); lp += e[16 + i]; }
    lsum += lp;
    // ---- pack P (own regs) + PV
    const char* Vbase = (const char*)&Vlds[buf][0];
    int c0 = cg * 64 + l31;
    int swv = (l31 & 7) << 4;  // c0&7 == (c0+32)&7 == l31&7
#pragma unroll
    for (int t = 0; t < 4; t++) {
      int base = (t >> 1) * 16 + (t & 1) * 8;
      h2 p0 = pk2(e[base + 0], e[base + 1]);
      h2 p1 = pk2(e[base + 2], e[base + 3]);
      h2 p2 = pk2(e[base + 4], e[base + 5]);
      h2 p3 = pk2(e[base + 6], e[base + 7]);
      f16x8 af = {p0[0], p0[1], p1[0], p1[1], p2[0], p2[1], p3[0], p3[1]};
      int ob = t * 32 + 8 * h5;
      __builtin_amdgcn_s_setprio(1);
      f16x4 v0a = *(const f16x4*)(Vbase + c0 * 128 + (ob ^ swv));
      f16x4 v0b = *(const f16x4*)(Vbase + c0 * 128 + ((ob + 16) ^ swv));
      o0 = MFMA32(af, cat8(v0a, v0b), o0);
      f16x4 v1a = *(const f16x4*)(Vbase + (c0 + 32) * 128 + (ob ^ swv));
      f16x4 v1b = *(const f16x4*)(Vbase + (c0 + 32) * 128 + ((ob + 16) ^ swv));
      o1 = MFMA32(af, cat8(v1a, v1b), o1);
      __builtin_amdgcn_s_setprio(0);
    }
    __syncthreads();
    buf ^= 1;
  }
#undef STAGE
  // final l merge across halves + normalize + store
  int2v pl = __builtin_amdgcn_permlane32_swap(asi(lsum), asi(lsum), false, false);
  float inv = 1.f / (asf(pl[0]) + asf(pl[1]));
  int nbase = qt * 64 + rg * 32;
#pragma unroll
  for (int reg = 0; reg < 16; reg++) {
    int qr = (reg & 3) + 8 * (reg >> 2) + 4 * h5;
    float iv = __shfl(inv, qr, 64);
    f16* dst = att + (((size_t)b * 4096 + nbase + qr) << 8) + cg * 64 + l31;
    dst[0] = (f16)(o0[reg] * iv);
    dst[32] = (f16)(o1[reg] * iv);
  }
}

// -------------------------------------------------------------------------
// Output GEMM: out[b][o][n] = sum_{k<512} Wcat[o][k] * Bcat[n][k], Bcat=[att|xT].
__global__ __launch_bounds__(256, 2)
void k_gemm_out(const f16* __restrict__ Wcat, const f16* __restrict__ att,
                const f16* __restrict__ xT, float* __restrict__ out) {
  __shared__ f16 Alds[128 * 64];
  __shared__ f16 Blds[128 * 64];
  int b = blockIdx.z, mt = blockIdx.y, nt = blockIdx.x;
  int lane = threadIdx.x & 63, wave = threadIdx.x >> 6;
  int wm = wave >> 1, wn = wave & 1;
  f32x4 acc[4][4];
#pragma unroll
  for (int mf = 0; mf < 4; mf++)
#pragma unroll
    for (int nf = 0; nf < 4; nf++) acc[mf][nf] = (f32x4){0, 0, 0, 0};
  const f16* Abase = Wcat + (size_t)(mt * 128) * 512;
  for (int k0 = 0; k0 < 512; k0 += 64) {
    __syncthreads();
#pragma unroll
    for (int i = 0; i < 4; i++) {
      int chunk = i * 256 + threadIdx.x;
      int row = chunk >> 3, cc = chunk & 7, scc = cc ^ (row & 7);
      gload16(Abase + row * 512 + k0 + scc * 8, (char*)Alds + (i * 256 + wave * 64) * 16);
    }
    const f16* Bcol = (k0 < 256) ? (att + (((size_t)b * 4096 + nt * 128) << 8))
                                 : (xT + (((size_t)b * 4096 + nt * 128) << 8));
    int kk = (k0 < 256) ? k0 : (k0 - 256);
#pragma unroll
    for (int i = 0; i < 4; i++) {
      int chunk = i * 256 + threadIdx.x;
      int row = chunk >> 3, cc = chunk & 7, scc = cc ^ (row & 7);
      gload16(Bcol + (row << 8) + kk + scc * 8, (char*)Blds + (i * 256 + wave * 64) * 16);
    }
    __syncthreads();
#pragma unroll
    for (int ks = 0; ks < 2; ks++) {
      int cb = ((lane >> 4) * 8 + ks * 32) * 2;
      f16x8 af[4], bf[4];
#pragma unroll
      for (int mf = 0; mf < 4; mf++) {
        int row = wm * 64 + mf * 16 + (lane & 15);
        af[mf] = *(const f16x8*)((const char*)Alds + row * 128 + (cb ^ ((row & 7) << 4)));
      }
#pragma unroll
      for (int nf = 0; nf < 4; nf++) {
        int row = wn * 64 + nf * 16 + (lane & 15);
        bf[nf] = *(const f16x8*)((const char*)Blds + row * 128 + (cb ^ ((row & 7) << 4)));
      }
#pragma unroll
      for (int mf = 0; mf < 4; mf++)
#pragma unroll
        for (int nf = 0; nf < 4; nf++) acc[mf][nf] = MFMA16(af[mf], bf[nf], acc[mf][nf]);
    }
  }
#pragma unroll
  for (int mf = 0; mf < 4; mf++)
#pragma unroll
    for (int nf = 0; nf < 4; nf++)
#pragma unroll
      for (int r = 0; r < 4; r++) {
        int oo = mt * 128 + wm * 64 + mf * 16 + (lane >> 4) * 4 + r;
        int n = nt * 128 + wn * 64 + nf * 16 + (lane & 15);
        out[(((size_t)b * 512 + oo) << 12) + n] = acc[mf][nf][r];
      }
}

// -------------------------------------------------------------------------
extern "C" void kernel_launch(void* const* d_in, const int* in_sizes, int n_in,
                              void* d_out, int out_size, void* d_ws, size_t ws_size,
                              hipStream_t stream) {
  const float* x = (const float*)d_in[0];
  const float* wt = (const float*)d_in[1];
  const float* wp = (const float*)d_in[2];
  const float* wg = (const float*)d_in[3];
  const float* wo = (const float*)d_in[4];
  const float* wr = (const float*)d_in[5];
  const float* gm = (const float*)d_in[6];
  float* out = (float*)d_out;
  char* ws = (char*)d_ws;
  const size_t MB = 1024 * 1024;
  f16* xT = (f16*)(ws);
  f16* Qb = (f16*)(ws + 16 * MB);
  f16* Kp = (f16*)(ws + 20 * MB);
  f16* Vb = (f16*)(ws + 21 * MB);
  f16* Wproj = (f16*)(ws + 25 * MB);
  f16* Wcat = (f16*)(ws + 25 * MB + 512 * 1024);
  f16* F = (f16*)(ws + 26 * MB);
  f16* att = F;  // alias: F fully consumed by k_pool before k_flash writes att

  hipLaunchKernelGGL(k_prep_w, dim3(1408), dim3(256), 0, stream, wt, wp, wg, wo, wr, gm,
                     Wproj, Wcat);
  hipLaunchKernelGGL(k_transpose, dim3(4, 64, 8), dim3(256), 0, stream, x, xT);
  hipLaunchKernelGGL(k_gemm_projq, dim3(32, 6, 8), dim3(256), 0, stream, xT, Wproj, Qb, F);
  hipLaunchKernelGGL(k_pool, dim3(320), dim3(256), 0, stream, F, Kp, Vb);
  hipLaunchKernelGGL(k_flash, dim3(64, 8), dim3(512), 0, stream, Qb, Kp, Vb, att);
  hipLaunchKernelGGL(k_gemm_out, dim3(32, 4, 8), dim3(256), 0, stream, Wcat, att, xT, out);
}